// Round 17
// baseline (162.607 us; speedup 1.0000x reference)
//
#include <hip/hip_runtime.h>
#include <hip/hip_bf16.h>

typedef short short8 __attribute__((ext_vector_type(8)));
typedef float f32x4 __attribute__((ext_vector_type(4)));
typedef unsigned int uint;

#define CB   16
#define TT   8
#define CIN  1024
#define ICH  512
#define HWS  196
#define NPB  1568   // cols per batch (196*8)
#define NF   25088  // flat cols = 16*1568

static __device__ __forceinline__ unsigned short f2bf(float f) {
  __hip_bfloat16 h = __float2bfloat16(f); unsigned short u; __builtin_memcpy(&u, &h, 2); return u;
}

// async global->LDS, 16B per lane; LDS dest is wave-uniform base + lane*16
static __device__ __forceinline__ void stage16(const void* g, void* l) {
  __builtin_amdgcn_global_load_lds(
      (const __attribute__((address_space(1))) unsigned int*)(unsigned long long)g,
      (__attribute__((address_space(3))) unsigned int*)(unsigned int)(unsigned long long)l,
      16, 0, 0);
}

// ---------------- weight prep (vectorized) ----------------
__global__ void k_prep_w(const float* __restrict__ w1, const float* __restrict__ w2,
    const float* __restrict__ wb1, const float* __restrict__ bb1,
    const float* __restrict__ wb2, const float* __restrict__ bb2,
    const float* __restrict__ wb3, const float* __restrict__ bb3,
    const float* __restrict__ wb4, const float* __restrict__ bb4,
    __hip_bfloat16* __restrict__ w1b, __hip_bfloat16* __restrict__ w2b,
    float* __restrict__ weff, float* __restrict__ beff) {
  int g = blockIdx.x * 256 + threadIdx.x;
  int idx4 = g * 4;
  if (idx4 < CIN * ICH) {
    float4 a = *(const float4*)(w1 + idx4);
    ushort4 pa = {f2bf(a.x), f2bf(a.y), f2bf(a.z), f2bf(a.w)};
    *(ushort4*)((unsigned short*)w1b + idx4) = pa;
    float4 b = *(const float4*)(w2 + idx4);
    ushort4 pb = {f2bf(b.x), f2bf(b.y), f2bf(b.z), f2bf(b.w)};
    *(ushort4*)((unsigned short*)w2b + idx4) = pb;
  }
  if (g < ICH) {
    float e[7];
#pragma unroll
    for (int u = 0; u < 7; u++) e[u] = wb4[g * 7 + u];
#pragma unroll
    for (int u = 0; u < 5; u++) e[u + 1] += wb3[g * 5 + u];
#pragma unroll
    for (int u = 0; u < 3; u++) e[u + 2] += wb2[g * 3 + u];
    e[3] += wb1[g];
#pragma unroll
    for (int u = 0; u < 7; u++) weff[g * 8 + u] = e[u];
    weff[g * 8 + 7] = 0.f;
    beff[g] = bb1[g] + bb2[g] + bb3[g] + bb4[g];
  }
}

// ---------------- GEMM1 with FUSED x-transpose A-staging + 7-tap conv epilogue ----------------
// 256(n) x 256(o) tile, BK=64, 16 waves. A comes straight from x (fp32, [bt][c][hw]):
//  - per thread: (t, cc, hwq) fixed; 4 float4 loads per K-tile (it -> t+=2); each float4
//    = 4 consecutive hw of one (b,t,c) -> rows hwq*32+j*8+t of the A-tile at col cc.
//    196 % 4 == 0 and float4s are 4-aligned in gidx => never straddle a b-boundary.
//  - LDS A write swizzle: slot = (c>>3) ^ (row&7) ^ ((row>>5)&7). row&7==t and bits>=5
//    of row can't affect banks via the 128-B stride, so both must enter via XOR.
//    Banks: slot varies with hwq(lane&7), sub-bank with cc&7(lane>>3) -> 2-way (free).
//  - read side compensates: raA[mf] uses chunk = lm ^ (row&7) ^ ((row>>5)&7); ck1 = ^32.
// Schedule per iter t (R12 skeleton, A-half gating removed -> 2 barriers, not 3):
//  p0: load av(t+1)x4; gload B-h0(t+1); vmcnt(5) [drains B(t); av not needed yet];
//      barrier; reads mf0,1/bfA @ck0; lgkm(0); MFMA G0
//  p1: gload B-h1(t+1); reads @ck1; lgkm(0); MFMA G1
//  p2: reads mf2,3 @ck0; lgkm(0); MFMA G2 (A fully written at p3(t-1), no wait needed)
//  p3: vmcnt(2) [drains av(t+1)]; 16x ds_write_b16 A(t+1)->buf nb; reads mf2,3 @ck1;
//      lgkm(0) [covers writes+reads]; barrier; MFMA G3
// FIFO: steady p0 issue-> [B0(t),B1(t),av x4,B0(t+1)] -> vmcnt(5); after p1: [av x4,B0,B1]
// -> p3 vmcnt(2). Last iter: p0 vmcnt(0), p3 skips write block, no end barrier.
// Restage safety: As[nb]/Bs[nb] last read in iter t-1 before its p3-barrier; any wave's
// iter-t writes/gloads issue after it passed that barrier (and p0-barrier) -> safe.
__global__ __launch_bounds__(1024, 4) void k_gemm1(const float* __restrict__ x,
                                                   const __hip_bfloat16* __restrict__ w1b,
                                                   const float* __restrict__ b1,
                                                   const float* __restrict__ weff,
                                                   const float* __restrict__ beff,
                                                   __hip_bfloat16* __restrict__ dwT) {
  __shared__ __hip_bfloat16 As[2 * 256 * 64];
  __shared__ __hip_bfloat16 Bs[2 * 256 * 64];
  int xcd = blockIdx.x & 7, i = blockIdx.x >> 3;
  int id = (xcd < 4 ? xcd * 25 : 100 + (xcd - 4) * 24) + i;  // bijective for 196
  int rt = id >> 1, ot = id & 1;   // ot-pair adjacent -> same XCD shares x panel
  int gidx0 = rt * 32, o0 = ot * 256;
  const int tid = threadIdx.x;
  const int lane = tid & 63, w = tid >> 6;
  const int wm = w >> 2, wn = w & 3;
  const int ln = lane & 15, lm = lane >> 4;

  // ---- A reg-staging setup ----
  const int hwq = lane & 7;                   // which float4 within the 32-hw run
  const int ccA = (w & 7) * 8 + (lane >> 3);  // c within K-tile [0,64)
  const int tA0 = (w >> 3);                   // t = tA0 + it*2
  int g4 = gidx0 + hwq * 4;
  int b4 = g4 / HWS;
  int hw4 = g4 - b4 * HWS;
  const float* xbase = x + ((size_t)(b4 * TT + tA0) * CIN + ccA) * HWS + hw4;
  const int wslot = (ccA >> 3);               // ^ t ^ hwq at write time
  unsigned short* AsW = (unsigned short*)As;

  // ---- B staging (gload_lds, unchanged) ----
  const int srow = lane >> 3;
  const int schk = (lane & 7) ^ srow;
  const __hip_bfloat16* bS = w1b + (size_t)(o0 + w * 8 + srow) * CIN + schk * 8;
  __hip_bfloat16* bD = Bs + (w * 8) * 64;
#define STGB(h, kt, buf) \
  stage16(bS + (size_t)((h) * 128) * CIN + (kt) * 64, bD + (buf) * 16384 + ((h) * 128) * 64)

  // ---- read-side offsets ----
  const int ckB0 = ((lm) ^ (ln & 7)) * 8;
  const int rbb = (wn * 64 + ln) * 64;
  int raA[4];
#pragma unroll
  for (int mf = 0; mf < 4; mf++) {
    int row = mf * 64 + wm * 16 + ln;
    int ch = lm ^ (row & 7) ^ ((row >> 5) & 7);
    raA[mf] = row * 64 + ch * 8;
  }

  f32x4 acc[4][4];
#pragma unroll
  for (int a = 0; a < 4; a++)
#pragma unroll
    for (int c = 0; c < 4; c++) acc[a][c] = (f32x4){0.f, 0.f, 0.f, 0.f};

  // ---- prologue: tile 0 ----
  f32x4 av0 = *(const f32x4*)(xbase);
  f32x4 av1 = *(const f32x4*)(xbase + 401408);      // 2*1024*196
  f32x4 av2 = *(const f32x4*)(xbase + 802816);
  f32x4 av3 = *(const f32x4*)(xbase + 1204224);
  STGB(0, 0, 0); STGB(1, 0, 0);
  asm volatile("s_waitcnt vmcnt(2)" ::: "memory");  // av landed; B(0) in flight
  {
#pragma unroll
    for (int it = 0; it < 4; it++) {
      f32x4 v = (it == 0) ? av0 : (it == 1) ? av1 : (it == 2) ? av2 : av3;
      int tt = tA0 + it * 2;
      int sb = (wslot ^ tt ^ hwq) * 8 + (ccA & 7);
#pragma unroll
      for (int j = 0; j < 4; j++)
        AsW[(hwq * 32 + j * 8 + tt) * 64 + sb] = f2bf(v[j]);
    }
  }
  asm volatile("s_waitcnt lgkmcnt(0)" ::: "memory");

  short8 af0, af1, bfA[4], bfB[4];
  for (int t = 0; t < 16; t++) {
    const int buf = t & 1, nb = buf ^ 1;
    const bool has = (t < 15);
    const __hip_bfloat16* Ab = As + buf * 16384;
    const __hip_bfloat16* Bb = Bs + buf * 16384;
    // ---- p0 ----
    if (has) {
      const float* pk = xbase + (size_t)(t + 1) * 12544;  // 64*196
      av0 = *(const f32x4*)pk;
      av1 = *(const f32x4*)(pk + 401408);
      av2 = *(const f32x4*)(pk + 802816);
      av3 = *(const f32x4*)(pk + 1204224);
      STGB(0, t + 1, nb);
      asm volatile("s_waitcnt vmcnt(5)" ::: "memory");
    } else {
      asm volatile("s_waitcnt vmcnt(0)" ::: "memory");
    }
    asm volatile("s_barrier" ::: "memory");  // B(t) visible (A written+fenced last iter)
    af0 = *(const short8*)&Ab[raA[0]];
    af1 = *(const short8*)&Ab[raA[1]];
#pragma unroll
    for (int nf = 0; nf < 4; nf++) bfA[nf] = *(const short8*)&Bb[rbb + nf * 1024 + ckB0];
    asm volatile("s_waitcnt lgkmcnt(0)" ::: "memory");
    __builtin_amdgcn_sched_barrier(0);
    __builtin_amdgcn_s_setprio(1);
#pragma unroll
    for (int nf = 0; nf < 4; nf++) {
      acc[0][nf] = __builtin_amdgcn_mfma_f32_16x16x32_bf16(af0, bfA[nf], acc[0][nf], 0, 0, 0);
      acc[1][nf] = __builtin_amdgcn_mfma_f32_16x16x32_bf16(af1, bfA[nf], acc[1][nf], 0, 0, 0);
    }
    __builtin_amdgcn_s_setprio(0);
    // ---- p1 ----
    if (has) STGB(1, t + 1, nb);
    af0 = *(const short8*)&Ab[raA[0] ^ 32];
    af1 = *(const short8*)&Ab[raA[1] ^ 32];
#pragma unroll
    for (int nf = 0; nf < 4; nf++) bfB[nf] = *(const short8*)&Bb[rbb + nf * 1024 + (ckB0 ^ 32)];
    asm volatile("s_waitcnt lgkmcnt(0)" ::: "memory");
    __builtin_amdgcn_sched_barrier(0);
    __builtin_amdgcn_s_setprio(1);
#pragma unroll
    for (int nf = 0; nf < 4; nf++) {
      acc[0][nf] = __builtin_amdgcn_mfma_f32_16x16x32_bf16(af0, bfB[nf], acc[0][nf], 0, 0, 0);
      acc[1][nf] = __builtin_amdgcn_mfma_f32_16x16x32_bf16(af1, bfB[nf], acc[1][nf], 0, 0, 0);
    }
    __builtin_amdgcn_s_setprio(0);
    // ---- p2 ----
    af0 = *(const short8*)&Ab[raA[2]];
    af1 = *(const short8*)&Ab[raA[3]];
    asm volatile("s_waitcnt lgkmcnt(0)" ::: "memory");
    __builtin_amdgcn_sched_barrier(0);
    __builtin_amdgcn_s_setprio(1);
#pragma unroll
    for (int nf = 0; nf < 4; nf++) {
      acc[2][nf] = __builtin_amdgcn_mfma_f32_16x16x32_bf16(af0, bfA[nf], acc[2][nf], 0, 0, 0);
      acc[3][nf] = __builtin_amdgcn_mfma_f32_16x16x32_bf16(af1, bfA[nf], acc[3][nf], 0, 0, 0);
    }
    __builtin_amdgcn_s_setprio(0);
    // ---- p3 ----
    if (has) {
      asm volatile("s_waitcnt vmcnt(2)" ::: "memory");  // av(t+1) landed
      unsigned short* dst = AsW + nb * 16384;
#pragma unroll
      for (int it = 0; it < 4; it++) {
        f32x4 v = (it == 0) ? av0 : (it == 1) ? av1 : (it == 2) ? av2 : av3;
        int tt = tA0 + it * 2;
        int sb = (wslot ^ tt ^ hwq) * 8 + (ccA & 7);
#pragma unroll
        for (int j = 0; j < 4; j++)
          dst[(hwq * 32 + j * 8 + tt) * 64 + sb] = f2bf(v[j]);
      }
    }
    af0 = *(const short8*)&Ab[raA[2] ^ 32];
    af1 = *(const short8*)&Ab[raA[3] ^ 32];
    asm volatile("s_waitcnt lgkmcnt(0)" ::: "memory");  // covers writes + reads
    __builtin_amdgcn_sched_barrier(0);
    if (has) asm volatile("s_barrier" ::: "memory");  // A(t+1)+... visible; restage-safe
    __builtin_amdgcn_s_setprio(1);
#pragma unroll
    for (int nf = 0; nf < 4; nf++) {
      acc[2][nf] = __builtin_amdgcn_mfma_f32_16x16x32_bf16(af0, bfB[nf], acc[2][nf], 0, 0, 0);
      acc[3][nf] = __builtin_amdgcn_mfma_f32_16x16x32_bf16(af1, bfB[nf], acc[3][nf], 0, 0, 0);
    }
    __builtin_amdgcn_s_setprio(0);
  }
#undef STGB

  // ---- fused 7-tap conv epilogue (unchanged; writes dwT) ----
  int n0 = rt * 256;
  bool hiT = (lm & 1);
#pragma unroll
  for (int nf = 0; nf < 4; nf++) {
    int o = o0 + wn * 64 + nf * 16 + ln;
    float e[7];
#pragma unroll
    for (int u = 0; u < 7; u++) e[u] = weff[o * 8 + u];
    float be = beff[o];
    float bo = b1[o];
#pragma unroll
    for (int mf = 0; mf < 4; mf++) {
      float av[4], pv[4];
#pragma unroll
      for (int j = 0; j < 4; j++) av[j] = acc[mf][nf][j] + bo;
#pragma unroll
      for (int j = 0; j < 4; j++) pv[j] = __shfl_xor(av[j], 16, 64);
      float ov[4];
      if (hiT) {
#pragma unroll
        for (int j = 0; j < 4; j++) {
          float s = be;
#pragma unroll
          for (int u = 0; u < 7; u++) {
            int ss = 4 + j + u - 3;
            if (ss >= 0 && ss < 8) s += e[u] * (ss < 4 ? pv[ss] : av[ss - 4]);
          }
          ov[j] = s;
        }
      } else {
#pragma unroll
        for (int j = 0; j < 4; j++) {
          float s = be;
#pragma unroll
          for (int u = 0; u < 7; u++) {
            int ss = j + u - 3;
            if (ss >= 0 && ss < 8) s += e[u] * (ss < 4 ? av[ss] : pv[ss - 4]);
          }
          ov[j] = s;
        }
      }
      int grow = n0 + mf * 64 + wm * 16 + ((lm >> 1) & 1) * 8;
      int gidx = grow >> 3;  // = b*196 + hw
      int gb = gidx / HWS, ghw = gidx - gb * HWS;
      int tb = hiT ? 4 : 0;
#pragma unroll
      for (int j = 0; j < 4; j++) {
        size_t rr = (size_t)gb * NPB + (size_t)(tb + j) * HWS + ghw;
        dwT[rr * ICH + o] = __float2bfloat16(ov[j]);
      }
    }
  }
}

// ---------------- 256x256 GEMM core (R12-proven) for gemm2 ----------------
template <int KD>
static __device__ __forceinline__ void gemm_core16(
    const __hip_bfloat16* __restrict__ Ar,
    const __hip_bfloat16* __restrict__ Br,
    __hip_bfloat16* As, __hip_bfloat16* Bs, f32x4 (&acc)[4][4]) {
  constexpr int NT = KD / 64;
  const int tid = threadIdx.x;
  const int lane = tid & 63, w = tid >> 6;
  const int wm = w >> 2, wn = w & 3;
  const int ln = lane & 15, lm = lane >> 4;
  const int srow = lane >> 3;
  const int schk = (lane & 7) ^ srow;
  const __hip_bfloat16* aS = Ar + (size_t)(w * 8 + srow) * KD + schk * 8;
  const __hip_bfloat16* bS = Br + (size_t)(w * 8 + srow) * KD + schk * 8;
  __hip_bfloat16* aD = As + (w * 8) * 64;
  __hip_bfloat16* bD = Bs + (w * 8) * 64;
  const int ck0 = ((lm) ^ (ln & 7)) * 8;
  const int ck1 = ((4 + lm) ^ (ln & 7)) * 8;
  const int rab = (wm * 16 + ln) * 64;
  const int rbb = (wn * 64 + ln) * 64;

#define STG(src, dst, h, kt, buf) \
  stage16(src + (size_t)((h) * 128) * KD + (kt) * 64, dst + (buf) * 16384 + ((h) * 128) * 64)

  STG(bS, bD, 0, 0, 0); STG(bS, bD, 1, 0, 0);
  STG(aS, aD, 0, 0, 0); STG(aS, aD, 1, 0, 0);

  short8 af0, af1, bfA[4], bfB[4];
  for (int t = 0; t < NT; t++) {
    const int buf = t & 1, nb = buf ^ 1;
    const bool has = (t + 1 < NT);
    const __hip_bfloat16* Ab = As + buf * 16384;
    const __hip_bfloat16* Bb = Bs + buf * 16384;
    if (has) STG(bS, bD, 0, t + 1, nb);
    if (has) asm volatile("s_waitcnt vmcnt(2)" ::: "memory");
    else     asm volatile("s_waitcnt vmcnt(1)" ::: "memory");
    asm volatile("s_barrier" ::: "memory");
    af0 = *(const short8*)&Ab[rab + ck0];
    af1 = *(const short8*)&Ab[rab + 4096 + ck0];
#pragma unroll
    for (int nf = 0; nf < 4; nf++) bfA[nf] = *(const short8*)&Bb[rbb + nf * 1024 + ck0];
    asm volatile("s_waitcnt lgkmcnt(0)" ::: "memory");
    __builtin_amdgcn_sched_barrier(0);
    __builtin_amdgcn_s_setprio(1);
#pragma unroll
    for (int nf = 0; nf < 4; nf++) {
      acc[0][nf] = __builtin_amdgcn_mfma_f32_16x16x32_bf16(af0, bfA[nf], acc[0][nf], 0, 0, 0);
      acc[1][nf] = __builtin_amdgcn_mfma_f32_16x16x32_bf16(af1, bfA[nf], acc[1][nf], 0, 0, 0);
    }
    __builtin_amdgcn_s_setprio(0);
    if (has) STG(bS, bD, 1, t + 1, nb);
    af0 = *(const short8*)&Ab[rab + ck1];
    af1 = *(const short8*)&Ab[rab + 4096 + ck1];
#pragma unroll
    for (int nf = 0; nf < 4; nf++) bfB[nf] = *(const short8*)&Bb[rbb + nf * 1024 + ck1];
    asm volatile("s_waitcnt lgkmcnt(0)" ::: "memory");
    __builtin_amdgcn_sched_barrier(0);
    __builtin_amdgcn_s_setprio(1);
#pragma unroll
    for (int nf = 0; nf < 4; nf++) {
      acc[0][nf] = __builtin_amdgcn_mfma_f32_16x16x32_bf16(af0, bfB[nf], acc[0][nf], 0, 0, 0);
      acc[1][nf] = __builtin_amdgcn_mfma_f32_16x16x32_bf16(af1, bfB[nf], acc[1][nf], 0, 0, 0);
    }
    __builtin_amdgcn_s_setprio(0);
    if (has) STG(aS, aD, 0, t + 1, nb);
    if (has) asm volatile("s_waitcnt vmcnt(3)" ::: "memory");
    else     asm volatile("s_waitcnt vmcnt(0)" ::: "memory");
    asm volatile("s_barrier" ::: "memory");
    af0 = *(const short8*)&Ab[rab + 2 * 4096 + ck0];
    af1 = *(const short8*)&Ab[rab + 3 * 4096 + ck0];
    asm volatile("s_waitcnt lgkmcnt(0)" ::: "memory");
    __builtin_amdgcn_sched_barrier(0);
    __builtin_amdgcn_s_setprio(1);
#pragma unroll
    for (int nf = 0; nf < 4; nf++) {
      acc[2][nf] = __builtin_amdgcn_mfma_f32_16x16x32_bf16(af0, bfA[nf], acc[2][nf], 0, 0, 0);
      acc[3][nf] = __builtin_amdgcn_mfma_f32_16x16x32_bf16(af1, bfA[nf], acc[3][nf], 0, 0, 0);
    }
    __builtin_amdgcn_s_setprio(0);
    if (has) STG(aS, aD, 1, t + 1, nb);
    af0 = *(const short8*)&Ab[rab + 2 * 4096 + ck1];
    af1 = *(const short8*)&Ab[rab + 3 * 4096 + ck1];
    asm volatile("s_waitcnt lgkmcnt(0)" ::: "memory");
    __builtin_amdgcn_sched_barrier(0);
    asm volatile("s_barrier" ::: "memory");
    __builtin_amdgcn_s_setprio(1);
#pragma unroll
    for (int nf = 0; nf < 4; nf++) {
      acc[2][nf] = __builtin_amdgcn_mfma_f32_16x16x32_bf16(af0, bfB[nf], acc[2][nf], 0, 0, 0);
      acc[3][nf] = __builtin_amdgcn_mfma_f32_16x16x32_bf16(af1, bfB[nf], acc[3][nf], 0, 0, 0);
    }
    __builtin_amdgcn_s_setprio(0);
  }
#undef STG
}

// ---------------- GEMM2 (unchanged, R16) ----------------
__global__ __launch_bounds__(1024, 4) void k_gemm2(const __hip_bfloat16* __restrict__ dwT,
                                                   const __hip_bfloat16* __restrict__ w2b,
                                                   const float* __restrict__ b2,
                                                   const float* __restrict__ xres,
                                                   float* __restrict__ out) {
  __shared__ __align__(16) char smem[131072];
  __hip_bfloat16* As = (__hip_bfloat16*)smem;
  __hip_bfloat16* Bs = (__hip_bfloat16*)(smem + 65536);
  int id = (blockIdx.x & 7) * 49 + (blockIdx.x >> 3);
  int nt = id >> 2, mt = id & 3;
  int n0 = nt * 256, m0 = mt * 256;
  f32x4 acc[4][4];
#pragma unroll
  for (int a = 0; a < 4; a++)
#pragma unroll
    for (int c = 0; c < 4; c++) acc[a][c] = (f32x4){0.f, 0.f, 0.f, 0.f};
  gemm_core16<512>(w2b + (size_t)m0 * ICH, dwT + (size_t)n0 * ICH, As, Bs, acc);

  int tid = threadIdx.x, lane = tid & 63, w = tid >> 6;
  int wm = w >> 2, wn = w & 3, ln = lane & 15, lm = lane >> 4;
  float* arr = (float*)smem;
  int fc = tid & 63, fr = tid >> 6;
  int n2 = n0 + fc * 4;
  int bb = n2 / NPB, r = n2 - bb * NPB;
  int t2 = r / HWS, hw = r - t2 * HWS;
  size_t base4 = ((size_t)((bb * TT + t2) * CIN)) * HWS + hw;
#pragma unroll
  for (int p = 0; p < 4; p++) {
    __syncthreads();
#pragma unroll
    for (int nf = 0; nf < 4; nf++)
#pragma unroll
      for (int j = 0; j < 4; j++)
        arr[(wm * 16 + lm * 4 + j) * 260 + wn * 64 + nf * 16 + ln] = acc[p][nf][j];
    __syncthreads();
#pragma unroll
    for (int it = 0; it < 4; it++) {
      int o2l = it * 16 + fr;
      f32x4 v = *(const f32x4*)&arr[o2l * 260 + fc * 4];
      int o2 = m0 + p * 64 + o2l;
      float bo = b2[o2];
      size_t a = base4 + (size_t)o2 * HWS;
      float4 xr = *(const float4*)(xres + a);
      float4 ov = make_float4(v[0] + bo + xr.x, v[1] + bo + xr.y,
                              v[2] + bo + xr.z, v[3] + bo + xr.w);
      *(float4*)(out + a) = ov;
    }
  }
}

extern "C" void kernel_launch(void* const* d_in, const int* in_sizes, int n_in,
                              void* d_out, int out_size, void* d_ws, size_t ws_size,
                              hipStream_t stream) {
  const float* x   = (const float*)d_in[0];
  const float* w1  = (const float*)d_in[1];
  const float* b1  = (const float*)d_in[2];
  const float* wb1 = (const float*)d_in[3];
  const float* bb1 = (const float*)d_in[4];
  const float* wb2 = (const float*)d_in[5];
  const float* bb2 = (const float*)d_in[6];
  const float* wb3 = (const float*)d_in[7];
  const float* bb3 = (const float*)d_in[8];
  const float* wb4 = (const float*)d_in[9];
  const float* bb4 = (const float*)d_in[10];
  const float* w2  = (const float*)d_in[11];
  const float* b2  = (const float*)d_in[12];
  float* out = (float*)d_out;

  // ws: dwT 25.69MB + w1b 1MB + w2b 1MB + weff 16KB + beff 2KB
  char* ws = (char*)d_ws;
  __hip_bfloat16* dwT = (__hip_bfloat16*)ws;
  __hip_bfloat16* w1b = (__hip_bfloat16*)(ws + 25690112);
  __hip_bfloat16* w2b = (__hip_bfloat16*)(ws + 25690112 + 1048576);
  float* weff = (float*)(ws + 25690112 + 2097152);
  float* beff = weff + 4096;

  k_prep_w<<<512, 256, 0, stream>>>(
      w1, w2, wb1, bb1, wb2, bb2, wb3, bb3, wb4, bb4, w1b, w2b, weff, beff);
  k_gemm1<<<196, 1024, 0, stream>>>(x, w1b, b1, weff, beff, dwT);
  k_gemm2<<<392, 1024, 0, stream>>>(dwT, w2b, b2, x, out);
}

// Round 18
// 117.394 us; speedup vs baseline: 1.3851x; 1.3851x over previous
//
#include <hip/hip_runtime.h>
#include <hip/hip_bf16.h>

typedef short short8 __attribute__((ext_vector_type(8)));
typedef float f32x4 __attribute__((ext_vector_type(4)));
typedef unsigned int uint;

#define CB   16
#define TT   8
#define CIN  1024
#define ICH  512
#define HWS  196
#define NPB  1568   // cols per batch (196*8)
#define NF   25088  // flat cols = 16*1568

static __device__ __forceinline__ unsigned short f2bf(float f) {
  __hip_bfloat16 h = __float2bfloat16(f); unsigned short u; __builtin_memcpy(&u, &h, 2); return u;
}

// async global->LDS, 16B per lane; LDS dest is wave-uniform base + lane*16
static __device__ __forceinline__ void stage16(const void* g, void* l) {
  __builtin_amdgcn_global_load_lds(
      (const __attribute__((address_space(1))) unsigned int*)(unsigned long long)g,
      (__attribute__((address_space(3))) unsigned int*)(unsigned int)(unsigned long long)l,
      16, 0, 0);
}

// ---------------- weight prep (vectorized: 4 elems/thread, 512 blocks) ----------------
__global__ void k_prep_w(const float* __restrict__ w1, const float* __restrict__ w2,
    const float* __restrict__ wb1, const float* __restrict__ bb1,
    const float* __restrict__ wb2, const float* __restrict__ bb2,
    const float* __restrict__ wb3, const float* __restrict__ bb3,
    const float* __restrict__ wb4, const float* __restrict__ bb4,
    __hip_bfloat16* __restrict__ w1b, __hip_bfloat16* __restrict__ w2b,
    float* __restrict__ weff, float* __restrict__ beff) {
  int g = blockIdx.x * 256 + threadIdx.x;   // 0..131071 (512 blocks)
  int idx4 = g * 4;
  if (idx4 < CIN * ICH) {
    float4 a = *(const float4*)(w1 + idx4);
    ushort4 pa = {f2bf(a.x), f2bf(a.y), f2bf(a.z), f2bf(a.w)};
    *(ushort4*)((unsigned short*)w1b + idx4) = pa;
    float4 b = *(const float4*)(w2 + idx4);
    ushort4 pb = {f2bf(b.x), f2bf(b.y), f2bf(b.z), f2bf(b.w)};
    *(ushort4*)((unsigned short*)w2b + idx4) = pb;
  }
  if (g < ICH) {
    float e[7];
#pragma unroll
    for (int u = 0; u < 7; u++) e[u] = wb4[g * 7 + u];
#pragma unroll
    for (int u = 0; u < 5; u++) e[u + 1] += wb3[g * 5 + u];
#pragma unroll
    for (int u = 0; u < 3; u++) e[u + 2] += wb2[g * 3 + u];
    e[3] += wb1[g];
#pragma unroll
    for (int u = 0; u < 7; u++) weff[g * 8 + u] = e[u];
    weff[g * 8 + 7] = 0.f;
    beff[g] = bb1[g] + bb2[g] + bb3[g] + bb4[g];
  }
}

// ---------------- x transpose v3 (R14-proven) ----------------
__global__ __launch_bounds__(448) void k_prep_x(const float* __restrict__ x,
                                                __hip_bfloat16* __restrict__ xbT) {
  __shared__ unsigned short tile[196 * 128];  // 50176 B
  int xcd = blockIdx.x & 7, i = blockIdx.x >> 3;
  int id = xcd * 128 + i;
  int bt = id >> 3, cr = id & 7;
  int c0 = cr * 128;
  int b = bt >> 3, t = bt & 7;
  const float* src = x + ((size_t)bt * CIN + c0) * HWS;
  int tid = threadIdx.x;
#pragma unroll
  for (int it = 0; it < 14; it++) {
    int idx = it * 448 + tid;               // = c*49 + hwq
    f32x4 v = *(const f32x4*)(src + (size_t)idx * 4);
    int c = idx / 49, hwq = idx - c * 49;
#pragma unroll
    for (int j = 0; j < 4; j++) {
      int hw = hwq * 4 + j;
      int slot = (c >> 3) ^ ((hw + (hw >> 2)) & 15);
      tile[hw * 128 + slot * 8 + (c & 7)] = f2bf(v[j]);
    }
  }
  __syncthreads();
  __hip_bfloat16* dstb = xbT + ((size_t)b * NPB + (size_t)t) * CIN + c0;
#pragma unroll
  for (int it = 0; it < 7; it++) {
    int idx = it * 448 + tid;               // = hw*16 + co
    int hw = idx >> 4, co = idx & 15;
    int slot = co ^ ((hw + (hw >> 2)) & 15);
    uint4 val = *(const uint4*)&tile[hw * 128 + slot * 8];
    *(uint4*)(dstb + (size_t)(hw * 8) * CIN + co * 8) = val;
  }
}

// ---------------- 256x256 GEMM core, BK=64, 16 waves (4x4), 64x64 per wave ----------------
// (R12/R14-proven best)
template <int KD>
static __device__ __forceinline__ void gemm_core16(
    const __hip_bfloat16* __restrict__ Ar,  // 256 rows x KD (k-contiguous)
    const __hip_bfloat16* __restrict__ Br,  // 256 rows x KD
    __hip_bfloat16* As, __hip_bfloat16* Bs, f32x4 (&acc)[4][4]) {
  constexpr int NT = KD / 64;
  const int tid = threadIdx.x;
  const int lane = tid & 63, w = tid >> 6;   // w 0..15
  const int wm = w >> 2, wn = w & 3;
  const int ln = lane & 15, lm = lane >> 4;
  const int srow = lane >> 3;                 // 0..7 (== row&7)
  const int schk = (lane & 7) ^ srow;
  const __hip_bfloat16* aS = Ar + (size_t)(w * 8 + srow) * KD + schk * 8;
  const __hip_bfloat16* bS = Br + (size_t)(w * 8 + srow) * KD + schk * 8;
  __hip_bfloat16* aD = As + (w * 8) * 64;
  __hip_bfloat16* bD = Bs + (w * 8) * 64;
  const int ck0 = ((lm) ^ (ln & 7)) * 8;
  const int ck1 = ((4 + lm) ^ (ln & 7)) * 8;
  const int rab = (wm * 16 + ln) * 64;  // + mf*4096
  const int rbb = (wn * 64 + ln) * 64;  // + nf*1024

#define STG(src, dst, h, kt, buf) \
  stage16(src + (size_t)((h) * 128) * KD + (kt) * 64, dst + (buf) * 16384 + ((h) * 128) * 64)

  STG(bS, bD, 0, 0, 0); STG(bS, bD, 1, 0, 0);
  STG(aS, aD, 0, 0, 0); STG(aS, aD, 1, 0, 0);

  short8 af0, af1, bfA[4], bfB[4];
  for (int t = 0; t < NT; t++) {
    const int buf = t & 1, nb = buf ^ 1;
    const bool has = (t + 1 < NT);
    const __hip_bfloat16* Ab = As + buf * 16384;
    const __hip_bfloat16* Bb = Bs + buf * 16384;
    // ---- p0: mf0,1 x ck0 ----
    if (has) STG(bS, bD, 0, t + 1, nb);
    if (has) asm volatile("s_waitcnt vmcnt(2)" ::: "memory");
    else     asm volatile("s_waitcnt vmcnt(1)" ::: "memory");
    asm volatile("s_barrier" ::: "memory");
    af0 = *(const short8*)&Ab[rab + ck0];
    af1 = *(const short8*)&Ab[rab + 4096 + ck0];
#pragma unroll
    for (int nf = 0; nf < 4; nf++) bfA[nf] = *(const short8*)&Bb[rbb + nf * 1024 + ck0];
    asm volatile("s_waitcnt lgkmcnt(0)" ::: "memory");
    __builtin_amdgcn_sched_barrier(0);
    __builtin_amdgcn_s_setprio(1);
#pragma unroll
    for (int nf = 0; nf < 4; nf++) {
      acc[0][nf] = __builtin_amdgcn_mfma_f32_16x16x32_bf16(af0, bfA[nf], acc[0][nf], 0, 0, 0);
      acc[1][nf] = __builtin_amdgcn_mfma_f32_16x16x32_bf16(af1, bfA[nf], acc[1][nf], 0, 0, 0);
    }
    __builtin_amdgcn_s_setprio(0);
    // ---- p1: mf0,1 x ck1 ----
    if (has) STG(bS, bD, 1, t + 1, nb);
    af0 = *(const short8*)&Ab[rab + ck1];
    af1 = *(const short8*)&Ab[rab + 4096 + ck1];
#pragma unroll
    for (int nf = 0; nf < 4; nf++) bfB[nf] = *(const short8*)&Bb[rbb + nf * 1024 + ck1];
    asm volatile("s_waitcnt lgkmcnt(0)" ::: "memory");
    __builtin_amdgcn_sched_barrier(0);
    __builtin_amdgcn_s_setprio(1);
#pragma unroll
    for (int nf = 0; nf < 4; nf++) {
      acc[0][nf] = __builtin_amdgcn_mfma_f32_16x16x32_bf16(af0, bfB[nf], acc[0][nf], 0, 0, 0);
      acc[1][nf] = __builtin_amdgcn_mfma_f32_16x16x32_bf16(af1, bfB[nf], acc[1][nf], 0, 0, 0);
    }
    __builtin_amdgcn_s_setprio(0);
    // ---- p2: mf2,3 x ck0 ----
    if (has) STG(aS, aD, 0, t + 1, nb);
    if (has) asm volatile("s_waitcnt vmcnt(3)" ::: "memory");
    else     asm volatile("s_waitcnt vmcnt(0)" ::: "memory");
    asm volatile("s_barrier" ::: "memory");
    af0 = *(const short8*)&Ab[rab + 2 * 4096 + ck0];
    af1 = *(const short8*)&Ab[rab + 3 * 4096 + ck0];
    asm volatile("s_waitcnt lgkmcnt(0)" ::: "memory");
    __builtin_amdgcn_sched_barrier(0);
    __builtin_amdgcn_s_setprio(1);
#pragma unroll
    for (int nf = 0; nf < 4; nf++) {
      acc[2][nf] = __builtin_amdgcn_mfma_f32_16x16x32_bf16(af0, bfA[nf], acc[2][nf], 0, 0, 0);
      acc[3][nf] = __builtin_amdgcn_mfma_f32_16x16x32_bf16(af1, bfA[nf], acc[3][nf], 0, 0, 0);
    }
    __builtin_amdgcn_s_setprio(0);
    // ---- p3: mf2,3 x ck1; end barrier before MFMAs ----
    if (has) STG(aS, aD, 1, t + 1, nb);
    af0 = *(const short8*)&Ab[rab + 2 * 4096 + ck1];
    af1 = *(const short8*)&Ab[rab + 3 * 4096 + ck1];
    asm volatile("s_waitcnt lgkmcnt(0)" ::: "memory");
    __builtin_amdgcn_sched_barrier(0);
    asm volatile("s_barrier" ::: "memory");
    __builtin_amdgcn_s_setprio(1);
#pragma unroll
    for (int nf = 0; nf < 4; nf++) {
      acc[2][nf] = __builtin_amdgcn_mfma_f32_16x16x32_bf16(af0, bfB[nf], acc[2][nf], 0, 0, 0);
      acc[3][nf] = __builtin_amdgcn_mfma_f32_16x16x32_bf16(af1, bfB[nf], acc[3][nf], 0, 0, 0);
    }
    __builtin_amdgcn_s_setprio(0);
  }
#undef STG
}

// ---------------- GEMM1 + fused 7-tap conv epilogue: writes dwT directly ----------------
__global__ __launch_bounds__(1024, 4) void k_gemm1(const __hip_bfloat16* __restrict__ xbT,
                                                   const __hip_bfloat16* __restrict__ w1b,
                                                   const float* __restrict__ b1,
                                                   const float* __restrict__ weff,
                                                   const float* __restrict__ beff,
                                                   __hip_bfloat16* __restrict__ dwT) {
  __shared__ __hip_bfloat16 As[2 * 256 * 64];
  __shared__ __hip_bfloat16 Bs[2 * 256 * 64];
  int xcd = blockIdx.x & 7, i = blockIdx.x >> 3;
  int id = (xcd < 4 ? xcd * 25 : 100 + (xcd - 4) * 24) + i;
  int rt = id >> 1, ot = id & 1;
  int n0 = rt * 256, o0 = ot * 256;
  f32x4 acc[4][4];
#pragma unroll
  for (int a = 0; a < 4; a++)
#pragma unroll
    for (int c = 0; c < 4; c++) acc[a][c] = (f32x4){0.f, 0.f, 0.f, 0.f};
  gemm_core16<1024>(xbT + (size_t)n0 * CIN, w1b + (size_t)o0 * CIN, As, Bs, acc);

  int tid = threadIdx.x, lane = tid & 63, w = tid >> 6;
  int wm = w >> 2, wn = w & 3, ln = lane & 15, lm = lane >> 4;
  bool hiT = (lm & 1);
#pragma unroll
  for (int nf = 0; nf < 4; nf++) {
    int o = o0 + wn * 64 + nf * 16 + ln;
    float e[7];
#pragma unroll
    for (int u = 0; u < 7; u++) e[u] = weff[o * 8 + u];
    float be = beff[o];
    float bo = b1[o];
#pragma unroll
    for (int mf = 0; mf < 4; mf++) {
      float av[4], pv[4];
#pragma unroll
      for (int j = 0; j < 4; j++) av[j] = acc[mf][nf][j] + bo;
#pragma unroll
      for (int j = 0; j < 4; j++) pv[j] = __shfl_xor(av[j], 16, 64);
      float ov[4];
      if (hiT) {
#pragma unroll
        for (int j = 0; j < 4; j++) {
          float s = be;
#pragma unroll
          for (int u = 0; u < 7; u++) {
            int ss = 4 + j + u - 3;
            if (ss >= 0 && ss < 8) s += e[u] * (ss < 4 ? pv[ss] : av[ss - 4]);
          }
          ov[j] = s;
        }
      } else {
#pragma unroll
        for (int j = 0; j < 4; j++) {
          float s = be;
#pragma unroll
          for (int u = 0; u < 7; u++) {
            int ss = j + u - 3;
            if (ss >= 0 && ss < 8) s += e[u] * (ss < 4 ? av[ss] : pv[ss - 4]);
          }
          ov[j] = s;
        }
      }
      int grow = n0 + mf * 64 + wm * 16 + ((lm >> 1) & 1) * 8;
      int gidx = grow >> 3;  // = b*196 + hw
      int gb = gidx / HWS, ghw = gidx - gb * HWS;
      int tb = hiT ? 4 : 0;
#pragma unroll
      for (int j = 0; j < 4; j++) {
        size_t rr = (size_t)gb * NPB + (size_t)(tb + j) * HWS + ghw;
        dwT[rr * ICH + o] = __float2bfloat16(ov[j]);
      }
    }
  }
}

// ---------------- GEMM2: out = w2b . dwT + b2 + residual; bounced float4 epilogue ----------------
__global__ __launch_bounds__(1024, 4) void k_gemm2(const __hip_bfloat16* __restrict__ dwT,
                                                   const __hip_bfloat16* __restrict__ w2b,
                                                   const float* __restrict__ b2,
                                                   const float* __restrict__ xres,
                                                   float* __restrict__ out) {
  __shared__ __align__(16) char smem[131072];
  __hip_bfloat16* As = (__hip_bfloat16*)smem;
  __hip_bfloat16* Bs = (__hip_bfloat16*)(smem + 65536);
  int id = (blockIdx.x & 7) * 49 + (blockIdx.x >> 3);
  int nt = id >> 2, mt = id & 3;
  int n0 = nt * 256, m0 = mt * 256;
  f32x4 acc[4][4];
#pragma unroll
  for (int a = 0; a < 4; a++)
#pragma unroll
    for (int c = 0; c < 4; c++) acc[a][c] = (f32x4){0.f, 0.f, 0.f, 0.f};
  gemm_core16<512>(w2b + (size_t)m0 * ICH, dwT + (size_t)n0 * ICH, As, Bs, acc);

  int tid = threadIdx.x, lane = tid & 63, w = tid >> 6;
  int wm = w >> 2, wn = w & 3, ln = lane & 15, lm = lane >> 4;
  float* arr = (float*)smem;  // bounce: [64 o2-rows][260 cols] fp32 per pass
  int fc = tid & 63, fr = tid >> 6;  // fr 0..15, wave-uniform
  int n2 = n0 + fc * 4;
  int bb = n2 / NPB, r = n2 - bb * NPB;
  int t2 = r / HWS, hw = r - t2 * HWS;
  size_t base4 = ((size_t)((bb * TT + t2) * CIN)) * HWS + hw;
#pragma unroll
  for (int p = 0; p < 4; p++) {
    __syncthreads();
#pragma unroll
    for (int nf = 0; nf < 4; nf++)
#pragma unroll
      for (int j = 0; j < 4; j++)
        arr[(wm * 16 + lm * 4 + j) * 260 + wn * 64 + nf * 16 + ln] = acc[p][nf][j];
    __syncthreads();
#pragma unroll
    for (int it = 0; it < 4; it++) {
      int o2l = it * 16 + fr;
      f32x4 v = *(const f32x4*)&arr[o2l * 260 + fc * 4];
      int o2 = m0 + p * 64 + o2l;
      float bo = b2[o2];
      size_t a = base4 + (size_t)o2 * HWS;
      float4 xr = *(const float4*)(xres + a);
      float4 ov = make_float4(v[0] + bo + xr.x, v[1] + bo + xr.y,
                              v[2] + bo + xr.z, v[3] + bo + xr.w);
      *(float4*)(out + a) = ov;
    }
  }
}

extern "C" void kernel_launch(void* const* d_in, const int* in_sizes, int n_in,
                              void* d_out, int out_size, void* d_ws, size_t ws_size,
                              hipStream_t stream) {
  const float* x   = (const float*)d_in[0];
  const float* w1  = (const float*)d_in[1];
  const float* b1  = (const float*)d_in[2];
  const float* wb1 = (const float*)d_in[3];
  const float* bb1 = (const float*)d_in[4];
  const float* wb2 = (const float*)d_in[5];
  const float* bb2 = (const float*)d_in[6];
  const float* wb3 = (const float*)d_in[7];
  const float* bb3 = (const float*)d_in[8];
  const float* wb4 = (const float*)d_in[9];
  const float* bb4 = (const float*)d_in[10];
  const float* w2  = (const float*)d_in[11];
  const float* b2  = (const float*)d_in[12];
  float* out = (float*)d_out;

  // d_out as scratch: xbT bf16 [NF][CIN] at offset 0 (51.4MB; dead before gemm2 writes out)
  __hip_bfloat16* xbT = (__hip_bfloat16*)d_out;

  // ws: dwT 25.69MB + w1b 1MB + w2b 1MB + weff 16KB + beff 2KB
  char* ws = (char*)d_ws;
  __hip_bfloat16* dwT = (__hip_bfloat16*)ws;
  __hip_bfloat16* w1b = (__hip_bfloat16*)(ws + 25690112);
  __hip_bfloat16* w2b = (__hip_bfloat16*)(ws + 25690112 + 1048576);
  float* weff = (float*)(ws + 25690112 + 2097152);
  float* beff = weff + 4096;

  k_prep_w<<<512, 256, 0, stream>>>(
      w1, w2, wb1, bb1, wb2, bb2, wb3, bb3, wb4, bb4, w1b, w2b, weff, beff);
  k_prep_x<<<1024, 448, 0, stream>>>(x, xbT);
  k_gemm1<<<196, 1024, 0, stream>>>(xbT, w1b, b1, weff, beff, dwT);
  k_gemm2<<<392, 1024, 0, stream>>>(dwT, w2b, b2, x, out);
}